// Round 10
// baseline (224.464 us; speedup 1.0000x reference)
//
#include <hip/hip_runtime.h>
#include <hip/hip_bf16.h>

// Problem constants
#define B_  16
#define C_  6
#define T_  512
#define S_  8

typedef __attribute__((ext_vector_type(8))) short bf16x8;
typedef __attribute__((ext_vector_type(4))) float f32x4;

__device__ __forceinline__ ushort f2bf(float f) {
    __hip_bfloat16 h = __float2bfloat16(f);
    return *reinterpret_cast<ushort*>(&h);
}
__device__ __forceinline__ float bfu2f(ushort u) {
    uint x = (uint)u << 16;
    union { uint u; float f; } c; c.u = x; return c.f;
}
__device__ __forceinline__ bf16x8 cvt8(float4 a, float4 b) {
    union { bf16x8 v; ushort u[8]; } r;
    r.u[0] = f2bf(a.x); r.u[1] = f2bf(a.y); r.u[2] = f2bf(a.z); r.u[3] = f2bf(a.w);
    r.u[4] = f2bf(b.x); r.u[5] = f2bf(b.y); r.u[6] = f2bf(b.z); r.u[7] = f2bf(b.w);
    return r.v;
}

// ---------------------------------------------------------------------------
// Two 512x512 transposes in one launch (Wk->WkT, Wv->WvT)
__global__ void transpose2(const float* __restrict__ s0, const float* __restrict__ s1,
                           float* __restrict__ d0, float* __restrict__ d1) {
    const float* src = blockIdx.z ? s1 : s0;
    float* dst = blockIdx.z ? d1 : d0;
    __shared__ float tile[32][33];
    int bx = blockIdx.x * 32, by = blockIdx.y * 32;
    int tx = threadIdx.x, ty = threadIdx.y;
    for (int i = 0; i < 32; i += 8)
        tile[ty + i][tx] = src[(long)(by + ty + i) * 512 + bx + tx];
    __syncthreads();
    for (int i = 0; i < 32; i += 8)
        dst[(long)(bx + ty + i) * 512 + by + tx] = tile[tx][ty + i];
}

// Two fp32->bf16 512x512 conversions in one launch (Wq, Wo)
__global__ void convert2(const float* __restrict__ s0, const float* __restrict__ s1,
                         ushort* __restrict__ d0, ushort* __restrict__ d1) {
    const float* s = blockIdx.y ? s1 : s0;
    ushort* d = blockIdx.y ? d1 : d0;
    int i = (blockIdx.x * 256 + threadIdx.x) * 4;
    float4 v = *(const float4*)(s + i);
    ushort4 o;
    o.x = f2bf(v.x); o.y = f2bf(v.y); o.z = f2bf(v.z); o.w = f2bf(v.w);
    *(ushort4*)(d + i) = o;
}

// ---------------------------------------------------------------------------
// K/V projections (tiny: 128 rows)
__global__ void kv_proj(const float* __restrict__ key, const float* __restrict__ value,
                        const float* __restrict__ WkT, const float* __restrict__ WvT,
                        const float* __restrict__ bk, const float* __restrict__ bv,
                        float* __restrict__ kout, float* __restrict__ vout) {
    int row = blockIdx.x;      // b*S + s
    int j = threadIdx.x;       // 0..511
    __shared__ float krow[512];
    __shared__ float vrow[512];
    krow[j] = key[(long)row * 512 + j];
    vrow[j] = value[(long)row * 512 + j];
    __syncthreads();
    float ak = bk[j], av = bv[j];
#pragma unroll 8
    for (int f = 0; f < 512; ++f) {
        ak += krow[f] * WkT[(long)f * 512 + j];
        av += vrow[f] * WvT[(long)f * 512 + j];
    }
    kout[(long)row * 512 + j] = ak;
    vout[(long)row * 512 + j] = av;
}

// ---------------------------------------------------------------------------
// Direct-fragment MFMA GEMM: ONE WAVE per 64x64 output tile. No LDS staging,
// no K-loop barriers. Each lane loads its MFMA fragments straight from
// global (dense 16-row x 64-128B segments, L1/L2-served for W; A streamed
// from HBM). A double-buffered in regs 1 step ahead; W reloaded after last
// use (WAR scoreboard). The fully-unrolled barrier-free loop keeps ~24KB per
// wave in flight -> BW-bound instead of barrier-drain latency-bound (the
// R4-R9 structures averaged <2KB in flight; Little's law needs ~22KB/CU).
// Epilogue stages via small per-block LDS for coalesced dwordx4 stores.
// out[m,n] = sum_k A[m,k]*W[n,k] + bias[n]; N=K=512. grid = mtiles*8 (%8==0).
// XCD swizzle: XCD x gets a contiguous mt-range, all 8 nt -> A L2-shared x8,
// W (512KB) L2-resident per XCD.
template <int ABF16, int OUTBF>
__global__ __launch_bounds__(64, 2)
void gemm_direct(const void* __restrict__ Ain, const ushort* __restrict__ Wbf,
                 const float* __restrict__ bias, void* __restrict__ out, int mtiles) {
    __shared__ __align__(16) char elds[OUTBF ? 8192 : 16384];

    const int bid  = blockIdx.x;
    const int virt = (bid & 7) * mtiles + (bid >> 3);   // nwg = mtiles*8, cpx = mtiles
    const int bm   = (virt >> 3) * 64;
    const int bn   = (virt & 7) * 64;
    const int lane = threadIdx.x;
    const int ln15 = lane & 15;
    const int ln16 = lane >> 4;

    f32x4 acc[4][4] = {};
    uint4 wb[4][2];   // W frags for current step (bf16x8 each)

    auto LOADW = [&](int k0) {
#pragma unroll
        for (int ni = 0; ni < 4; ++ni)
#pragma unroll
            for (int kj = 0; kj < 2; ++kj)
                wb[ni][kj] = *(const uint4*)(Wbf + (long)(bn + ni * 16 + ln15) * 512
                                             + k0 + kj * 32 + ln16 * 8);
    };

    if (ABF16) {
        const ushort* A = (const ushort*)Ain;
        uint4 ab[2][4][2];
        auto LOADA = [&](uint4 (&d)[4][2], int k0) {
#pragma unroll
            for (int mi = 0; mi < 4; ++mi)
#pragma unroll
                for (int kj = 0; kj < 2; ++kj)
                    d[mi][kj] = *(const uint4*)(A + (long)(bm + mi * 16 + ln15) * 512
                                                + k0 + kj * 32 + ln16 * 8);
        };
        LOADA(ab[0], 0);
        LOADW(0);
#pragma unroll
        for (int kt = 0; kt < 8; ++kt) {
            if (kt < 7) LOADA(ab[(kt + 1) & 1], (kt + 1) * 64);
#pragma unroll
            for (int kj = 0; kj < 2; ++kj)
#pragma unroll
                for (int mi = 0; mi < 4; ++mi)
#pragma unroll
                    for (int ni = 0; ni < 4; ++ni)
                        acc[mi][ni] = __builtin_amdgcn_mfma_f32_16x16x32_bf16(
                            *(const bf16x8*)&ab[kt & 1][mi][kj],
                            *(const bf16x8*)&wb[ni][kj], acc[mi][ni], 0, 0, 0);
            if (kt < 7) LOADW((kt + 1) * 64);   // WAR-safe: all uses above issued
        }
    } else {
        const float* A = (const float*)Ain;
        float4 ab[2][4][2][2];   // [buf][mi][kj][half] : 128 VGPR
        auto LOADA = [&](float4 (&d)[4][2][2], int k0) {
#pragma unroll
            for (int mi = 0; mi < 4; ++mi)
#pragma unroll
                for (int kj = 0; kj < 2; ++kj) {
                    const float* p = A + (long)(bm + mi * 16 + ln15) * 512
                                     + k0 + kj * 32 + ln16 * 8;
                    d[mi][kj][0] = *(const float4*)p;
                    d[mi][kj][1] = *(const float4*)(p + 4);
                }
        };
        LOADA(ab[0], 0);
        LOADW(0);
#pragma unroll
        for (int kt = 0; kt < 8; ++kt) {
            if (kt < 7) LOADA(ab[(kt + 1) & 1], (kt + 1) * 64);
#pragma unroll
            for (int kj = 0; kj < 2; ++kj) {
                bf16x8 af[4];
#pragma unroll
                for (int mi = 0; mi < 4; ++mi)
                    af[mi] = cvt8(ab[kt & 1][mi][kj][0], ab[kt & 1][mi][kj][1]);
#pragma unroll
                for (int mi = 0; mi < 4; ++mi)
#pragma unroll
                    for (int ni = 0; ni < 4; ++ni)
                        acc[mi][ni] = __builtin_amdgcn_mfma_f32_16x16x32_bf16(
                            af[mi], *(const bf16x8*)&wb[ni][kj], acc[mi][ni], 0, 0, 0);
            }
            if (kt < 7) LOADW((kt + 1) * 64);
        }
    }

    // ---- epilogue: LDS-staged coalesced stores (per-wave 64x64 tile) ----
    float bsv[4];
#pragma unroll
    for (int ni = 0; ni < 4; ++ni)
        bsv[ni] = bias[bn + ni * 16 + ln15];

    if (OUTBF) {
        ushort* eb = (ushort*)elds;   // 64x64 bf16 = 8 KB
#pragma unroll
        for (int mi = 0; mi < 4; ++mi)
#pragma unroll
            for (int j = 0; j < 4; ++j) {
                int row = mi * 16 + ln16 * 4 + j;
#pragma unroll
                for (int ni = 0; ni < 4; ++ni) {
                    int col = ni * 16 + ln15;
                    eb[row * 64 + (col ^ ((row & 12) << 2))] = f2bf(acc[mi][ni][j] + bsv[ni]);
                }
            }
        __syncthreads();
#pragma unroll
        for (int p = 0; p < 8; ++p) {
            int row = p * 8 + (lane >> 3);
            int col = (lane & 7) * 8;
            int cs  = col ^ ((row & 12) << 2);
            uint4 v = *(const uint4*)&eb[row * 64 + cs];
            *(uint4*)((ushort*)out + (long)(bm + row) * 512 + bn + col) = v;
        }
    } else {
        float* ef = (float*)elds;     // 64x64 fp32 = 16 KB
#pragma unroll
        for (int mi = 0; mi < 4; ++mi)
#pragma unroll
            for (int j = 0; j < 4; ++j) {
                int row = mi * 16 + ln16 * 4 + j;
#pragma unroll
                for (int ni = 0; ni < 4; ++ni) {
                    int col = ni * 16 + ln15;
                    ef[row * 64 + (col ^ ((row & 12) << 2))] = acc[mi][ni][j] + bsv[ni];
                }
            }
        __syncthreads();
#pragma unroll
        for (int p = 0; p < 16; ++p) {
            int row = p * 4 + (lane >> 4);
            int col = (lane & 15) * 4;
            int cs  = col ^ ((row & 12) << 2);
            float4 v = *(const float4*)&ef[row * 64 + cs];
            *(float4*)((float*)out + (long)(bm + row) * 512 + bn + col) = v;
        }
    }
}

// ---------------------------------------------------------------------------
// Fused q1_mean + stage1 + stage2. One wave per (b,t). x out in bf16.
// qbf rows are NATURAL (b,c,t) order: row (b*6+c)*512 + t.
__global__ __launch_bounds__(64) void fused_attn(const ushort* __restrict__ qbf,
                                                 const float* __restrict__ kproj,
                                                 const float* __restrict__ vproj,
                                                 const int* __restrict__ mask,
                                                 ushort* __restrict__ xout) {
    int bt = blockIdx.x;
    int b = bt >> 9, t = bt & 511;
    int lane = threadIdx.x;

    __shared__ ushort qlds[6 * 512];
    __shared__ float q1l[512];
    __shared__ float pcl[512];
    __shared__ float ssl[48];
    __shared__ float a2l[48];

#pragma unroll
    for (int i = 0; i < 6; ++i) {
        long base = ((long)(b * 6 + i) * 512 + t) * 512;
        *(uint4*)&qlds[i * 512 + lane * 8] = *(const uint4*)(qbf + base + lane * 8);
    }
    __syncthreads();

    {
        float s[8] = {};
#pragma unroll
        for (int c = 0; c < 6; ++c) {
            const ushort* qr = &qlds[c * 512 + lane * 8];
#pragma unroll
            for (int j = 0; j < 8; ++j) s[j] += bfu2f(qr[j]);
        }
#pragma unroll
        for (int j = 0; j < 8; ++j) q1l[lane * 8 + j] = s[j] * (1.0f / 6.0f);
    }
    __syncthreads();

    int h = lane >> 3, s = lane & 7;
    const float* krow = kproj + (long)(b * S_ + s) * 512 + h * 64;
    float sc = 0.f;
#pragma unroll
    for (int d = 0; d < 64; d += 4) {
        float4 kv = *(const float4*)(krow + d);
        sc += q1l[h * 64 + d]     * kv.x;
        sc += q1l[h * 64 + d + 1] * kv.y;
        sc += q1l[h * 64 + d + 2] * kv.z;
        sc += q1l[h * 64 + d + 3] * kv.w;
    }
    sc *= 0.125f;
    int mk = mask[((long)b * T_ + t) * S_ + s];
    if (mk == 0) sc = -1e30f;
    float mx = sc;
    for (int off = 1; off < 8; off <<= 1) mx = fmaxf(mx, __shfl_xor(mx, off));
    float e = __expf(sc - mx);
    float sum = e;
    for (int off = 1; off < 8; off <<= 1) sum += __shfl_xor(sum, off);
    float attn = e / sum;
    if (mk == 0) attn = 0.f;

#pragma unroll
    for (int i = 0; i < 8; ++i) {
        float acc = 0.f;
#pragma unroll
        for (int s2 = 0; s2 < 8; ++s2) {
            float a = __shfl(attn, i * 8 + s2);
            acc += a * vproj[(long)(b * S_ + s2) * 512 + i * 64 + lane];
        }
        pcl[i * 64 + lane] = acc;
    }
    __syncthreads();

    if (lane < 48) {
        int hh = lane / 6, cc = lane % 6;
        const float* pr = &pcl[hh * 64];
        const ushort* qr = &qlds[cc * 512 + hh * 64];
        float acc = 0.f;
#pragma unroll 8
        for (int d = 0; d < 64; ++d) acc += pr[d] * bfu2f(qr[d]);
        ssl[lane] = acc * 0.125f;
    }
    __syncthreads();
    if (lane < 8) {
        float mx2 = -1e30f;
#pragma unroll
        for (int c = 0; c < 6; ++c) mx2 = fmaxf(mx2, ssl[lane * 6 + c]);
        float ex[6];
        float sm = 0.f;
#pragma unroll
        for (int c = 0; c < 6; ++c) {
            ex[c] = __expf(ssl[lane * 6 + c] - mx2);
            sm += ex[c];
        }
        float inv = 1.0f / sm;
#pragma unroll
        for (int c = 0; c < 6; ++c) a2l[lane * 6 + c] = ex[c] * inv;
    }
    __syncthreads();

#pragma unroll
    for (int i = 0; i < 8; ++i) {
        float acc = 0.f;
#pragma unroll
        for (int c = 0; c < 6; ++c)
            acc += a2l[i * 6 + c] * bfu2f(qlds[c * 512 + i * 64 + lane]);
        xout[(long)bt * 512 + i * 64 + lane] = f2bf(acc);
    }
}

// ---------------------------------------------------------------------------
extern "C" void kernel_launch(void* const* d_in, const int* in_sizes, int n_in,
                              void* d_out, int out_size, void* d_ws, size_t ws_size,
                              hipStream_t stream) {
    const float* query = (const float*)d_in[0];
    const float* key   = (const float*)d_in[1];
    const float* value = (const float*)d_in[2];
    const int*   mask  = (const int*)d_in[3];
    const float* Wq = (const float*)d_in[4];
    const float* bq = (const float*)d_in[5];
    const float* Wk = (const float*)d_in[6];
    const float* bk = (const float*)d_in[7];
    const float* Wv = (const float*)d_in[8];
    const float* bv = (const float*)d_in[9];
    const float* Wo = (const float*)d_in[10];
    const float* bo = (const float*)d_in[11];
    float* out = (float*)d_out;

    char* ws = (char*)d_ws;
    ushort* Wqbf  = (ushort*)(ws + 0);                  // 512 KB
    ushort* Wobf  = (ushort*)(ws + 524288u);            // 512 KB
    float*  WkT   = (float*)(ws + (1u << 20));          // 1 MB
    float*  WvT   = (float*)(ws + (2u << 20));          // 1 MB
    float*  kproj = (float*)(ws + (3u << 20));          // 256 KB
    float*  vproj = (float*)(ws + (3u << 20) + 262144u);
    ushort* qbf   = (ushort*)(ws + (4u << 20));         // 48 MB, rows (b,c,t)
    ushort* xbf   = (ushort*)(ws + 54525952u);          // 8 MB (8192 x 512 bf16)

    convert2<<<dim3(256, 2), 256, 0, stream>>>(Wq, Wo, Wqbf, Wobf);
    transpose2<<<dim3(16, 16, 2), dim3(32, 8), 0, stream>>>(Wk, Wv, WkT, WvT);

    kv_proj<<<B_ * S_, 512, 0, stream>>>(key, value, WkT, WvT, bk, bv, kproj, vproj);

    // Q projection: M = 49152 rows NATURAL (b,c,t), fp32 A, bf16 out
    // mtiles = 49152/64 = 768, grid = 6144 (1 wave per block)
    gemm_direct<0, 1><<<6144, 64, 0, stream>>>(query, Wqbf, bq, qbf, 768);

    // fused q1_mean + stage1 + stage2 -> x (bf16)
    fused_attn<<<B_ * T_, 64, 0, stream>>>(qbf, kproj, vproj, mask, xbf);

    // output projection: M = 8192, bf16 A, fp32 out; mtiles = 128, grid = 1024
    gemm_direct<1, 0><<<1024, 64, 0, stream>>>(xbf, Wobf, bo, out, 128);

    (void)in_sizes; (void)n_in; (void)out_size; (void)ws_size;
}

// Round 11
// 193.851 us; speedup vs baseline: 1.1579x; 1.1579x over previous
//
#include <hip/hip_runtime.h>
#include <hip/hip_bf16.h>

// Problem constants
#define B_  16
#define C_  6
#define T_  512
#define S_  8

#define AS1 __attribute__((address_space(1)))
#define AS3 __attribute__((address_space(3)))

typedef __attribute__((ext_vector_type(8))) short bf16x8;
typedef __attribute__((ext_vector_type(4))) float f32x4;

__device__ __forceinline__ ushort f2bf(float f) {
    __hip_bfloat16 h = __float2bfloat16(f);
    return *reinterpret_cast<ushort*>(&h);
}
__device__ __forceinline__ float bfu2f(ushort u) {
    uint x = (uint)u << 16;
    union { uint u; float f; } c; c.u = x; return c.f;
}

// ---------------------------------------------------------------------------
// Two 512x512 transposes in one launch (Wk->WkT, Wv->WvT)
__global__ void transpose2(const float* __restrict__ s0, const float* __restrict__ s1,
                           float* __restrict__ d0, float* __restrict__ d1) {
    const float* src = blockIdx.z ? s1 : s0;
    float* dst = blockIdx.z ? d1 : d0;
    __shared__ float tile[32][33];
    int bx = blockIdx.x * 32, by = blockIdx.y * 32;
    int tx = threadIdx.x, ty = threadIdx.y;
    for (int i = 0; i < 32; i += 8)
        tile[ty + i][tx] = src[(long)(by + ty + i) * 512 + bx + tx];
    __syncthreads();
    for (int i = 0; i < 32; i += 8)
        dst[(long)(bx + ty + i) * 512 + by + tx] = tile[tx][ty + i];
}

// Two fp32->bf16 512x512 conversions in one launch (Wq, Wo)
__global__ void convert2(const float* __restrict__ s0, const float* __restrict__ s1,
                         ushort* __restrict__ d0, ushort* __restrict__ d1) {
    const float* s = blockIdx.y ? s1 : s0;
    ushort* d = blockIdx.y ? d1 : d0;
    int i = (blockIdx.x * 256 + threadIdx.x) * 4;
    float4 v = *(const float4*)(s + i);
    ushort4 o;
    o.x = f2bf(v.x); o.y = f2bf(v.y); o.z = f2bf(v.z); o.w = f2bf(v.w);
    *(ushort4*)(d + i) = o;
}

// ---------------------------------------------------------------------------
// K/V projections (tiny: 128 rows)
__global__ void kv_proj(const float* __restrict__ key, const float* __restrict__ value,
                        const float* __restrict__ WkT, const float* __restrict__ WvT,
                        const float* __restrict__ bk, const float* __restrict__ bv,
                        float* __restrict__ kout, float* __restrict__ vout) {
    int row = blockIdx.x;      // b*S + s
    int j = threadIdx.x;       // 0..511
    __shared__ float krow[512];
    __shared__ float vrow[512];
    krow[j] = key[(long)row * 512 + j];
    vrow[j] = value[(long)row * 512 + j];
    __syncthreads();
    float ak = bk[j], av = bv[j];
#pragma unroll 8
    for (int f = 0; f < 512; ++f) {
        ak += krow[f] * WkT[(long)f * 512 + j];
        av += vrow[f] * WvT[(long)f * 512 + j];
    }
    kout[(long)row * 512 + j] = ak;
    vout[(long)row * 512 + j] = av;
}

// ---------------------------------------------------------------------------
// MEGA-FUSED kernel: per block = 8 consecutive (b,t) rows.
//  Ph1: stage 48 query rows (c=0..5 x 8 t) -> Alds bf16, XOR-swizzled chunks
//  Ph2: q[48,512] = A @ Wq^T + bq via MFMA (M=48 = 3 frags, full efficiency).
//       B-frags streamed from L2-resident Wq-bf16 with a 4-deep register ring.
//       q -> qlds bf16 (48 KB). Never touches HBM.
//  Ph3: q1 = mean_c q
//  Ph4: stage-1 attention (proven code; k/v projections from L2)
//  Ph5: ss[bt,h,c] = pc_h . q_{c,h} * 0.125; softmax over c
//  Ph6: x = sum_c attn2_c * q_c  -> xout bf16 (feeds output projection GEMM)
// Replaces the standalone 49152-row q-projection GEMM + fused_attn and kills
// 96 MB of qbf HBM traffic. LDS ~134 KB -> 1 block/CU, 4 waves.
__global__ __launch_bounds__(256) void qattn(const float* __restrict__ query,
                                             const ushort* __restrict__ Wqbf,
                                             const float* __restrict__ bq,
                                             const float* __restrict__ kproj,
                                             const float* __restrict__ vproj,
                                             const int* __restrict__ mask,
                                             ushort* __restrict__ xout) {
    __shared__ __align__(16) ushort Alds[48 * 512];   // 48 KB staged query bf16 (swizzled)
    __shared__ __align__(16) ushort qlds[48 * 512];   // 48 KB q result bf16 (linear)
    __shared__ float q1l[8 * 512];                    // 16 KB
    __shared__ float pcl[8 * 512];                    // 16 KB
    __shared__ float ssl[8 * 8 * 6];
    __shared__ float a2l[8 * 8 * 6];

    const int b   = blockIdx.x >> 6;
    const int t0  = (blockIdx.x & 63) << 3;
    const int tid = threadIdx.x;
    const int w    = tid >> 6;
    const int lane = tid & 63;
    const int ln15 = lane & 15;
    const int ln16 = lane >> 4;

    // ---- Phase 1: stage 48 query rows -> Alds (bf16, 8-elem chunk XOR r&7) ----
    {
        int r  = tid >> 4;              // 0..15
        int kc = (tid & 15) * 32;       // f-offset (32 floats per thread per rep)
#pragma unroll
        for (int rep = 0; rep < 3; ++rep) {
            int row = rep * 16 + r;     // 0..47 ; row = c*8 + j
            int c = row >> 3, j = row & 7;
            const float* src = query + ((long)(b * 6 + c) * 512 + (t0 + j)) * 512 + kc;
            float4 v[8];
#pragma unroll
            for (int q = 0; q < 8; ++q) v[q] = *(const float4*)(src + q * 4);
#pragma unroll
            for (int q = 0; q < 4; ++q) {
                uint4 pk;
                pk.x = (uint)f2bf(v[2*q].x)   | ((uint)f2bf(v[2*q].y)   << 16);
                pk.y = (uint)f2bf(v[2*q].z)   | ((uint)f2bf(v[2*q].w)   << 16);
                pk.z = (uint)f2bf(v[2*q+1].x) | ((uint)f2bf(v[2*q+1].y) << 16);
                pk.w = (uint)f2bf(v[2*q+1].z) | ((uint)f2bf(v[2*q+1].w) << 16);
                int c8 = (kc >> 3) + q;
                *(uint4*)&Alds[row * 512 + (((c8 & 7) ^ (row & 7)) << 3) + ((c8 >> 3) << 6)] = pk;
            }
        }
    }
    __syncthreads();

    // ---- Phase 2: q = A @ Wq^T + bq (per wave: 32-col window per n-chunk) ----
    for (int nc = 0; nc < 4; ++nc) {
        const int n0 = nc * 128 + w * 32;
        f32x4 acc[3][2] = {};
        uint4 br[4][2];                 // 4-deep B ring (Wq rows from L2)
#pragma unroll
        for (int kb = 0; kb < 3; ++kb)
#pragma unroll
            for (int nf = 0; nf < 2; ++nf)
                br[kb][nf] = *(const uint4*)(Wqbf + (long)(n0 + nf * 16 + ln15) * 512
                                             + kb * 32 + ln16 * 8);
#pragma unroll
        for (int kb = 0; kb < 16; ++kb) {
            if (kb < 13) {
#pragma unroll
                for (int nf = 0; nf < 2; ++nf)
                    br[(kb + 3) & 3][nf] = *(const uint4*)(Wqbf + (long)(n0 + nf * 16 + ln15) * 512
                                                           + (kb + 3) * 32 + ln16 * 8);
            }
            bf16x8 af[3];
#pragma unroll
            for (int mf = 0; mf < 3; ++mf) {
                int row = mf * 16 + ln15;
                int c8  = kb * 4 + ln16;
                af[mf] = *(const bf16x8*)&Alds[row * 512 + (((c8 & 7) ^ (row & 7)) << 3) + ((c8 >> 3) << 6)];
            }
#pragma unroll
            for (int mf = 0; mf < 3; ++mf)
#pragma unroll
                for (int nf = 0; nf < 2; ++nf)
                    acc[mf][nf] = __builtin_amdgcn_mfma_f32_16x16x32_bf16(
                        af[mf], *(const bf16x8*)&br[kb & 3][nf], acc[mf][nf], 0, 0, 0);
        }
#pragma unroll
        for (int nf = 0; nf < 2; ++nf) {
            float bs = bq[n0 + nf * 16 + ln15];
#pragma unroll
            for (int mf = 0; mf < 3; ++mf)
#pragma unroll
                for (int j = 0; j < 4; ++j) {
                    int row = mf * 16 + ln16 * 4 + j;
                    qlds[row * 512 + n0 + nf * 16 + ln15] = f2bf(acc[mf][nf][j] + bs);
                }
        }
    }
    __syncthreads();

    // ---- Phase 3: q1 = mean over c ----
    {
        int btl = tid >> 5, f0 = (tid & 31) << 4;
        float s[16] = {};
#pragma unroll
        for (int c = 0; c < 6; ++c) {
            const ushort* qr = &qlds[(c * 8 + btl) * 512 + f0];
#pragma unroll
            for (int q = 0; q < 16; ++q) s[q] += bfu2f(qr[q]);
        }
        float* dst = &q1l[btl * 512 + f0];
#pragma unroll
        for (int q = 0; q < 16; ++q) dst[q] = s[q] * (1.0f / 6.0f);
    }
    __syncthreads();

    // ---- Phase 4: stage-1 attention (2 bt per wave) ----
#pragma unroll
    for (int rep = 0; rep < 2; ++rep) {
        int btl = w * 2 + rep;
        int t = t0 + btl;
        int h = lane >> 3, s = lane & 7;
        const float* krow = kproj + (long)(b * S_ + s) * 512 + h * 64;
        const float* q1r  = &q1l[btl * 512 + h * 64];
        float sc = 0.f;
#pragma unroll
        for (int d = 0; d < 64; d += 4) {
            float4 kv = *(const float4*)(krow + d);
            sc += q1r[d]     * kv.x;
            sc += q1r[d + 1] * kv.y;
            sc += q1r[d + 2] * kv.z;
            sc += q1r[d + 3] * kv.w;
        }
        sc *= 0.125f;
        int mk = mask[((long)b * T_ + t) * S_ + s];
        if (mk == 0) sc = -1e30f;
        float mx = sc;
        for (int off = 1; off < 8; off <<= 1) mx = fmaxf(mx, __shfl_xor(mx, off));
        float e = __expf(sc - mx);
        float sum = e;
        for (int off = 1; off < 8; off <<= 1) sum += __shfl_xor(sum, off);
        float attn = e / sum;
        if (mk == 0) attn = 0.f;
#pragma unroll
        for (int i = 0; i < 8; ++i) {
            float acc = 0.f;
#pragma unroll
            for (int s2 = 0; s2 < 8; ++s2) {
                float a = __shfl(attn, i * 8 + s2);
                acc += a * vproj[(long)(b * S_ + s2) * 512 + i * 64 + lane];
            }
            pcl[btl * 512 + i * 64 + lane] = acc;
        }
    }
    __syncthreads();

    // ---- Phase 5: ss[bt,h,c] = pc_h . q_{c,h} * 0.125 ; softmax over c ----
    for (int jb = tid; jb < 384; jb += 256) {
        int c = jb % 6; int tmp = jb / 6; int h = tmp & 7; int btl = tmp >> 3;
        const float* pr  = &pcl[btl * 512 + h * 64];
        const ushort* qr = &qlds[(c * 8 + btl) * 512 + h * 64];
        float acc = 0.f;
#pragma unroll 8
        for (int d = 0; d < 64; ++d) acc += pr[d] * bfu2f(qr[d]);
        ssl[jb] = acc * 0.125f;
    }
    __syncthreads();
    if (tid < 64) {
        int btl = tid >> 3, h = tid & 7;
        const float* sp = &ssl[(btl * 8 + h) * 6];
        float mx2 = -1e30f;
#pragma unroll
        for (int c = 0; c < 6; ++c) mx2 = fmaxf(mx2, sp[c]);
        float ex[6];
        float sm = 0.f;
#pragma unroll
        for (int c = 0; c < 6; ++c) {
            ex[c] = __expf(sp[c] - mx2);
            sm += ex[c];
        }
        float inv = 1.0f / sm;
        float* ap = &a2l[(btl * 8 + h) * 6];
#pragma unroll
        for (int c = 0; c < 6; ++c) ap[c] = ex[c] * inv;
    }
    __syncthreads();

    // ---- Phase 6: x = sum_c attn2_c * q_c -> global bf16 ----
    {
        int btl = tid >> 5, f0 = (tid & 31) << 4;
        int h = f0 >> 6;
        const float* a2 = &a2l[(btl * 8 + h) * 6];
        float s[16] = {};
#pragma unroll
        for (int c = 0; c < 6; ++c) {
            float a = a2[c];
            const ushort* qr = &qlds[(c * 8 + btl) * 512 + f0];
#pragma unroll
            for (int q = 0; q < 16; ++q) s[q] += a * bfu2f(qr[q]);
        }
        ushort* dst = xout + ((long)(b * T_ + t0 + btl)) * 512 + f0;
        uint4 o0, o1;
        o0.x = (uint)f2bf(s[0])  | ((uint)f2bf(s[1])  << 16);
        o0.y = (uint)f2bf(s[2])  | ((uint)f2bf(s[3])  << 16);
        o0.z = (uint)f2bf(s[4])  | ((uint)f2bf(s[5])  << 16);
        o0.w = (uint)f2bf(s[6])  | ((uint)f2bf(s[7])  << 16);
        o1.x = (uint)f2bf(s[8])  | ((uint)f2bf(s[9])  << 16);
        o1.y = (uint)f2bf(s[10]) | ((uint)f2bf(s[11]) << 16);
        o1.z = (uint)f2bf(s[12]) | ((uint)f2bf(s[13]) << 16);
        o1.w = (uint)f2bf(s[14]) | ((uint)f2bf(s[15]) << 16);
        *(uint4*)dst = o0;
        *(uint4*)(dst + 8) = o1;
    }
}

// ---------------------------------------------------------------------------
// MFMA bf16 GEMM (R9 structure) — used for the output projection only.
// ABF16: both operands via global_load_lds, dbuf, single barrier per step.
template <int ABF16, int OUTBF>
__global__ __launch_bounds__(256, ABF16 ? 2 : 3)
void gemm_mfma(const void* __restrict__ Ain,
               const ushort* __restrict__ Wbf,
               const float* __restrict__ bias,
               void* __restrict__ out, int mpanels) {
    __shared__ __align__(16) ushort lds[ABF16 ? 32768 : 24576];

    const int bid = blockIdx.x;
    const int cpx = (mpanels * 4) >> 3;
    const int swz = (bid & 7) * cpx + (bid >> 3);
    const int bm = (swz >> 2) * 128;
    const int bn = (swz & 3) * 128;

    const int tid  = threadIdx.x;
    const int lane = tid & 63;
    const int wv   = tid >> 6;
    const int wm   = (wv >> 1) * 64;
    const int wn   = (wv & 1) * 64;
    const int ln15 = lane & 15;
    const int ln16 = lane >> 4;

    auto GLDS = [&](const ushort* gbase, int rowbase, ushort* ldsbase, int k0) {
        int rb = wv * 32 + (lane >> 3);
        int c  = lane & 7;
#pragma unroll
        for (int i = 0; i < 4; ++i) {
            int r = rb + i * 8;
            const ushort* src = gbase + (long)(rowbase + r) * 512 + k0 + ((c ^ (r & 7)) << 3);
            ushort* dst = ldsbase + wv * 2048 + i * 512;
            __builtin_amdgcn_global_load_lds((AS1 const void*)src, (AS3 void*)dst, 16, 0, 0);
        }
    };

    ushort* asb0 = lds;
    ushort* asb1 = lds + 8192;
    ushort* wsb[2] = { lds + 16384, lds + 24576 };

    f32x4 acc[4][4] = {};

    auto MFMA_PHASE = [&](ushort* Asb, ushort* Wsb) {
        __builtin_amdgcn_s_setprio(1);
#pragma unroll
        for (int kj = 0; kj < 2; ++kj) {
            bf16x8 af[4], bfv[4];
#pragma unroll
            for (int mi = 0; mi < 4; ++mi) {
                int row = wm + mi * 16 + ln15;
                int ch  = kj * 4 + ln16;
                af[mi] = *(const bf16x8*)&Asb[row * 64 + ((ch ^ (row & 7)) << 3)];
            }
#pragma unroll
            for (int ni = 0; ni < 4; ++ni) {
                int row = wn + ni * 16 + ln15;
                int ch  = kj * 4 + ln16;
                bfv[ni] = *(const bf16x8*)&Wsb[row * 64 + ((ch ^ (row & 7)) << 3)];
            }
#pragma unroll
            for (int mi = 0; mi < 4; ++mi)
#pragma unroll
                for (int ni = 0; ni < 4; ++ni)
                    acc[mi][ni] = __builtin_amdgcn_mfma_f32_16x16x32_bf16(
                        af[mi], bfv[ni], acc[mi][ni], 0, 0, 0);
        }
        __builtin_amdgcn_s_setprio(0);
    };

    GLDS((const ushort*)Ain, bm, asb0, 0);
    GLDS(Wbf, bn, wsb[0], 0);
    asm volatile("s_waitcnt vmcnt(0) lgkmcnt(0)" ::: "memory");
    __builtin_amdgcn_sched_barrier(0);
    __builtin_amdgcn_s_barrier();
    asm volatile("" ::: "memory");
#pragma unroll
    for (int kt = 0; kt < 8; ++kt) {
        ushort* Asb = (kt & 1) ? asb1 : asb0;
        ushort* nAs = (kt & 1) ? asb0 : asb1;
        if (kt < 7) {
            GLDS(Wbf, bn, wsb[(kt + 1) & 1], (kt + 1) * 64);
            GLDS((const ushort*)Ain, bm, nAs, (kt + 1) * 64);
        }
        __builtin_amdgcn_sched_barrier(0);
        MFMA_PHASE(Asb, wsb[kt & 1]);
        asm volatile("s_waitcnt vmcnt(0) lgkmcnt(0)" ::: "memory");
        __builtin_amdgcn_sched_barrier(0);
        __builtin_amdgcn_s_barrier();
        asm volatile("" ::: "memory");
    }

    float bsv[4];
#pragma unroll
    for (int ni = 0; ni < 4; ++ni)
        bsv[ni] = bias[bn + wn + ni * 16 + ln15];

    // fp32 out: stage in two 64-row halves (32 KB each)
    float* ef = (float*)lds;
#pragma unroll
    for (int half = 0; half < 2; ++half) {
        if (wm == half * 64) {
#pragma unroll
            for (int mi = 0; mi < 4; ++mi)
#pragma unroll
                for (int j = 0; j < 4; ++j) {
                    int lr = mi * 16 + ln16 * 4 + j;
#pragma unroll
                    for (int ni = 0; ni < 4; ++ni) {
                        int col = wn + ni * 16 + ln15;
                        int cs  = col ^ ((lr & 12) << 2);
                        ef[lr * 128 + cs] = acc[mi][ni][j] + bsv[ni];
                    }
                }
        }
        asm volatile("s_waitcnt lgkmcnt(0)" ::: "memory");
        __builtin_amdgcn_sched_barrier(0);
        __builtin_amdgcn_s_barrier();
        asm volatile("" ::: "memory");
#pragma unroll
        for (int i = 0; i < 8; ++i) {
            int idx = i * 1024 + tid * 4;
            int lr = idx >> 7, col = idx & 127;
            int cs = col ^ ((lr & 12) << 2);
            float4 v = *(const float4*)&ef[lr * 128 + cs];
            *(float4*)((float*)out + (long)(bm + half * 64 + lr) * 512 + bn + col) = v;
        }
        if (half == 0) {
            asm volatile("" ::: "memory");
            __builtin_amdgcn_s_barrier();
            asm volatile("" ::: "memory");
        }
    }
}

// ---------------------------------------------------------------------------
extern "C" void kernel_launch(void* const* d_in, const int* in_sizes, int n_in,
                              void* d_out, int out_size, void* d_ws, size_t ws_size,
                              hipStream_t stream) {
    const float* query = (const float*)d_in[0];
    const float* key   = (const float*)d_in[1];
    const float* value = (const float*)d_in[2];
    const int*   mask  = (const int*)d_in[3];
    const float* Wq = (const float*)d_in[4];
    const float* bq = (const float*)d_in[5];
    const float* Wk = (const float*)d_in[6];
    const float* bk = (const float*)d_in[7];
    const float* Wv = (const float*)d_in[8];
    const float* bv = (const float*)d_in[9];
    const float* Wo = (const float*)d_in[10];
    const float* bo = (const float*)d_in[11];
    float* out = (float*)d_out;

    char* ws = (char*)d_ws;
    ushort* Wqbf  = (ushort*)(ws + 0);                  // 512 KB
    ushort* Wobf  = (ushort*)(ws + 524288u);            // 512 KB
    float*  WkT   = (float*)(ws + (1u << 20));          // 1 MB
    float*  WvT   = (float*)(ws + (2u << 20));          // 1 MB
    float*  kproj = (float*)(ws + (3u << 20));          // 256 KB
    float*  vproj = (float*)(ws + (3u << 20) + 262144u);
    ushort* xbf   = (ushort*)(ws + (4u << 20));         // 8 MB (8192 x 512 bf16)

    convert2<<<dim3(256, 2), 256, 0, stream>>>(Wq, Wo, Wqbf, Wobf);
    transpose2<<<dim3(16, 16, 2), dim3(32, 8), 0, stream>>>(Wk, Wv, WkT, WvT);

    kv_proj<<<B_ * S_, 512, 0, stream>>>(key, value, WkT, WvT, bk, bv, kproj, vproj);

    // fused q-projection + two-stage attention: 1024 blocks x 8 (b,t) rows
    qattn<<<1024, 256, 0, stream>>>(query, Wqbf, bq, kproj, vproj, mask, xbf);

    // output projection: M = 8192, bf16 A, fp32 out
    gemm_mfma<1, 0><<<256, 256, 0, stream>>>(xbf, Wobf, bo, out, 64);

    (void)in_sizes; (void)n_in; (void)out_size; (void)ws_size;
}

// Round 12
// 114.942 us; speedup vs baseline: 1.9529x; 1.6865x over previous
//
#include <hip/hip_runtime.h>
#include <hip/hip_bf16.h>

// Problem constants
#define B_  16
#define C_  6
#define T_  512
#define S_  8

#define AS1 __attribute__((address_space(1)))
#define AS3 __attribute__((address_space(3)))

typedef __attribute__((ext_vector_type(8))) short bf16x8;
typedef __attribute__((ext_vector_type(4))) float f32x4;

__device__ __forceinline__ ushort f2bf(float f) {
    __hip_bfloat16 h = __float2bfloat16(f);
    return *reinterpret_cast<ushort*>(&h);
}
__device__ __forceinline__ float bfu2f(ushort u) {
    uint x = (uint)u << 16;
    union { uint u; float f; } c; c.u = x; return c.f;
}

// ---------------------------------------------------------------------------
// Two 512x512 transposes in one launch (Wk->WkT, Wv->WvT)
__global__ void transpose2(const float* __restrict__ s0, const float* __restrict__ s1,
                           float* __restrict__ d0, float* __restrict__ d1) {
    const float* src = blockIdx.z ? s1 : s0;
    float* dst = blockIdx.z ? d1 : d0;
    __shared__ float tile[32][33];
    int bx = blockIdx.x * 32, by = blockIdx.y * 32;
    int tx = threadIdx.x, ty = threadIdx.y;
    for (int i = 0; i < 32; i += 8)
        tile[ty + i][tx] = src[(long)(by + ty + i) * 512 + bx + tx];
    __syncthreads();
    for (int i = 0; i < 32; i += 8)
        dst[(long)(bx + ty + i) * 512 + by + tx] = tile[tx][ty + i];
}

// Two fp32->bf16 512x512 conversions in one launch (Wq, Wo)
__global__ void convert2(const float* __restrict__ s0, const float* __restrict__ s1,
                         ushort* __restrict__ d0, ushort* __restrict__ d1) {
    const float* s = blockIdx.y ? s1 : s0;
    ushort* d = blockIdx.y ? d1 : d0;
    int i = (blockIdx.x * 256 + threadIdx.x) * 4;
    float4 v = *(const float4*)(s + i);
    ushort4 o;
    o.x = f2bf(v.x); o.y = f2bf(v.y); o.z = f2bf(v.z); o.w = f2bf(v.w);
    *(ushort4*)(d + i) = o;
}

// ---------------------------------------------------------------------------
// K/V projections (tiny: 128 rows)
__global__ void kv_proj(const float* __restrict__ key, const float* __restrict__ value,
                        const float* __restrict__ WkT, const float* __restrict__ WvT,
                        const float* __restrict__ bk, const float* __restrict__ bv,
                        float* __restrict__ kout, float* __restrict__ vout) {
    int row = blockIdx.x;      // b*S + s
    int j = threadIdx.x;       // 0..511
    __shared__ float krow[512];
    __shared__ float vrow[512];
    krow[j] = key[(long)row * 512 + j];
    vrow[j] = value[(long)row * 512 + j];
    __syncthreads();
    float ak = bk[j], av = bv[j];
#pragma unroll 8
    for (int f = 0; f < 512; ++f) {
        ak += krow[f] * WkT[(long)f * 512 + j];
        av += vrow[f] * WvT[(long)f * 512 + j];
    }
    kout[(long)row * 512 + j] = ak;
    vout[(long)row * 512 + j] = av;
}

// ---------------------------------------------------------------------------
// MEGA-FUSED v2: block = 16 t-rows of one b; 512 threads = 8 waves; WAVE = HEAD.
// Everything after the q-GEMM is head-local (all reductions are over d within
// one head), so wave w computes the q-GEMM n-window [w*64, w*64+64) and keeps
// q ENTIRELY IN ITS MFMA ACCUMULATORS acc[6c][4nf] (rows = c*16+tt via
// (ln16,j), cols = d via ln15). No qlds, no qbf, no phase-5 LDS reads.
//  Ph1: stage A = 96 query rows (6c x 16t) -> Alds bf16 swizzled (96 KB)
//  Ph2: q = A @ Wq^T + bq. A-frags broadcast from LDS (same addr all waves);
//       W streamed from L2 via distance-2 register ring. acc += bq.
//  Ph3: q1f[nf] = mean_c acc[c][nf]           (pure VALU)
//  Ph4: scores = q1.k (shfl_xor reduce over ln15=d), masked softmax over s,
//       pcf = attn @ v                         (k,v rows from L2)
//  Ph5: ss[tt][c] = pcf . acc[c] (shfl reduce), softmax over c
//  Ph6: xf = sum_c a2[c]*acc[c]; stage to LDS (reuse Alds), coalesced store.
__global__ __launch_bounds__(512, 2) void qattn(const float* __restrict__ query,
                                                const ushort* __restrict__ Wqbf,
                                                const float* __restrict__ bq,
                                                const float* __restrict__ kproj,
                                                const float* __restrict__ vproj,
                                                const int* __restrict__ mask,
                                                ushort* __restrict__ xout) {
    __shared__ __align__(16) ushort Alds[96 * 512];   // 96 KB
    __shared__ int mlds[128];

    const int b   = blockIdx.x >> 5;
    const int t0  = (blockIdx.x & 31) << 4;
    const int tid = threadIdx.x;
    const int h    = tid >> 6;          // wave = head
    const int lane = tid & 63;
    const int ln15 = lane & 15;
    const int ln16 = lane >> 4;
    const int nb   = h * 64;

    // ---- Phase 1: stage 96 query rows -> Alds (bf16, 8-chunk XOR row&7) ----
    if (tid < 128) mlds[tid] = mask[((long)b * 512 + t0 + (tid >> 3)) * 8 + (tid & 7)];
#pragma unroll
    for (int rep = 0; rep < 3; ++rep) {
        int item = rep * 512 + tid;
        int row = item >> 4;            // 0..95 = c*16 + tt
        int kc  = (item & 15) * 32;     // float offset
        int c = row >> 4, tt = row & 15;
        const float* src = query + ((long)(b * 6 + c) * 512 + t0 + tt) * 512 + kc;
        float4 v[8];
#pragma unroll
        for (int q = 0; q < 8; ++q) v[q] = *(const float4*)(src + q * 4);
#pragma unroll
        for (int q2 = 0; q2 < 4; ++q2) {
            uint4 pk;
            pk.x = (uint)f2bf(v[2*q2].x)   | ((uint)f2bf(v[2*q2].y)   << 16);
            pk.y = (uint)f2bf(v[2*q2].z)   | ((uint)f2bf(v[2*q2].w)   << 16);
            pk.z = (uint)f2bf(v[2*q2+1].x) | ((uint)f2bf(v[2*q2+1].y) << 16);
            pk.w = (uint)f2bf(v[2*q2+1].z) | ((uint)f2bf(v[2*q2+1].w) << 16);
            int c8 = (kc >> 3) + q2;
            *(uint4*)&Alds[row * 512 + (((c8 & 7) ^ (row & 7)) << 3) + ((c8 >> 3) << 6)] = pk;
        }
    }
    __syncthreads();

    // ---- Phase 2: q-GEMM, q stays in acc ----
    f32x4 acc[6][4] = {};
    uint4 br2[2][4];
#pragma unroll
    for (int nf = 0; nf < 4; ++nf) {
        br2[0][nf] = *(const uint4*)(Wqbf + (long)(nb + nf * 16 + ln15) * 512 + ln16 * 8);
        br2[1][nf] = *(const uint4*)(Wqbf + (long)(nb + nf * 16 + ln15) * 512 + 32 + ln16 * 8);
    }
#pragma unroll
    for (int kb = 0; kb < 16; ++kb) {
        bf16x8 af[6];
#pragma unroll
        for (int mf = 0; mf < 6; ++mf) {
            int row = mf * 16 + ln15;
            int c8  = kb * 4 + ln16;
            af[mf] = *(const bf16x8*)&Alds[row * 512 + (((c8 & 7) ^ (row & 7)) << 3) + ((c8 >> 3) << 6)];
        }
#pragma unroll
        for (int mf = 0; mf < 6; ++mf)
#pragma unroll
            for (int nf = 0; nf < 4; ++nf)
                acc[mf][nf] = __builtin_amdgcn_mfma_f32_16x16x32_bf16(
                    af[mf], *(const bf16x8*)&br2[kb & 1][nf], acc[mf][nf], 0, 0, 0);
        if (kb < 14) {
#pragma unroll
            for (int nf = 0; nf < 4; ++nf)
                br2[kb & 1][nf] = *(const uint4*)(Wqbf + (long)(nb + nf * 16 + ln15) * 512
                                                  + (kb + 2) * 32 + ln16 * 8);
        }
    }
    {
        float bqv[4];
#pragma unroll
        for (int nf = 0; nf < 4; ++nf) bqv[nf] = bq[nb + nf * 16 + ln15];
#pragma unroll
        for (int mf = 0; mf < 6; ++mf)
#pragma unroll
            for (int nf = 0; nf < 4; ++nf)
#pragma unroll
                for (int j = 0; j < 4; ++j) acc[mf][nf][j] += bqv[nf];
    }
    __syncthreads();   // all waves done reading Alds (freed for x-stage)

    // ---- Phase 3: q1 = mean over c (frag-elementwise) ----
    f32x4 q1f[4];
#pragma unroll
    for (int nf = 0; nf < 4; ++nf) {
        f32x4 s = acc[0][nf];
#pragma unroll
        for (int c = 1; c < 6; ++c) s += acc[c][nf];
        q1f[nf] = s * (1.0f / 6.0f);
    }

    // ---- Phase 4: stage-1 attention (head-local) ----
    float sc[4][8];
#pragma unroll
    for (int s = 0; s < 8; ++s) {
        float kv[4];
#pragma unroll
        for (int nf = 0; nf < 4; ++nf)
            kv[nf] = kproj[(long)(b * 8 + s) * 512 + nb + nf * 16 + ln15];
#pragma unroll
        for (int j = 0; j < 4; ++j) {
            float p = q1f[0][j] * kv[0] + q1f[1][j] * kv[1]
                    + q1f[2][j] * kv[2] + q1f[3][j] * kv[3];
            p += __shfl_xor(p, 1); p += __shfl_xor(p, 2);
            p += __shfl_xor(p, 4); p += __shfl_xor(p, 8);
            sc[j][s] = p * 0.125f;
        }
    }
    float attn[4][8];
#pragma unroll
    for (int j = 0; j < 4; ++j) {
        int tt = ln16 * 4 + j;
        int mk[8];
        float mx = -1e30f;
#pragma unroll
        for (int s = 0; s < 8; ++s) {
            mk[s] = mlds[tt * 8 + s];
            if (mk[s] == 0) sc[j][s] = -1e30f;
            mx = fmaxf(mx, sc[j][s]);
        }
        float sum = 0.f;
#pragma unroll
        for (int s = 0; s < 8; ++s) {
            float e = __expf(sc[j][s] - mx);
            attn[j][s] = e;
            sum += e;
        }
        float inv = 1.0f / sum;
#pragma unroll
        for (int s = 0; s < 8; ++s) attn[j][s] = mk[s] ? attn[j][s] * inv : 0.f;
    }
    f32x4 pcf[4] = {};
#pragma unroll
    for (int s = 0; s < 8; ++s) {
        float vv[4];
#pragma unroll
        for (int nf = 0; nf < 4; ++nf)
            vv[nf] = vproj[(long)(b * 8 + s) * 512 + nb + nf * 16 + ln15];
#pragma unroll
        for (int nf = 0; nf < 4; ++nf)
#pragma unroll
            for (int j = 0; j < 4; ++j) pcf[nf][j] += attn[j][s] * vv[nf];
    }

    // ---- Phase 5: ss + softmax over c (head-local) ----
    float a2[4][6];
#pragma unroll
    for (int c = 0; c < 6; ++c)
#pragma unroll
        for (int j = 0; j < 4; ++j) {
            float p = pcf[0][j] * acc[c][0][j] + pcf[1][j] * acc[c][1][j]
                    + pcf[2][j] * acc[c][2][j] + pcf[3][j] * acc[c][3][j];
            p += __shfl_xor(p, 1); p += __shfl_xor(p, 2);
            p += __shfl_xor(p, 4); p += __shfl_xor(p, 8);
            a2[j][c] = p * 0.125f;
        }
#pragma unroll
    for (int j = 0; j < 4; ++j) {
        float mx = -1e30f;
#pragma unroll
        for (int c = 0; c < 6; ++c) mx = fmaxf(mx, a2[j][c]);
        float sum = 0.f;
#pragma unroll
        for (int c = 0; c < 6; ++c) {
            float e = __expf(a2[j][c] - mx);
            a2[j][c] = e;
            sum += e;
        }
        float inv = 1.0f / sum;
#pragma unroll
        for (int c = 0; c < 6; ++c) a2[j][c] *= inv;
    }

    // ---- Phase 6: x = sum_c a2_c * q_c ; stage via LDS; coalesced store ----
    ushort* xstage = Alds;   // 16 rows x 512, Alds is dead
#pragma unroll
    for (int nf = 0; nf < 4; ++nf)
#pragma unroll
        for (int j = 0; j < 4; ++j) {
            float x = 0.f;
#pragma unroll
            for (int c = 0; c < 6; ++c) x += a2[j][c] * acc[c][nf][j];
            xstage[(ln16 * 4 + j) * 512 + nb + nf * 16 + ln15] = f2bf(x);
        }
    __syncthreads();
    {
        int idx = tid * 16;
        int row = idx >> 9;
        int off = idx & 511;
        uint4 v0 = *(const uint4*)&xstage[row * 512 + off];
        uint4 v1 = *(const uint4*)&xstage[row * 512 + off + 8];
        ushort* dst = xout + ((long)(b * 512 + t0 + row)) * 512 + off;
        *(uint4*)dst = v0;
        *(uint4*)(dst + 8) = v1;
    }
}

// ---------------------------------------------------------------------------
// MFMA bf16 GEMM (R9 structure) — output projection only (ABF16 path).
template <int ABF16, int OUTBF>
__global__ __launch_bounds__(256, ABF16 ? 2 : 3)
void gemm_mfma(const void* __restrict__ Ain,
               const ushort* __restrict__ Wbf,
               const float* __restrict__ bias,
               void* __restrict__ out, int mpanels) {
    __shared__ __align__(16) ushort lds[32768];

    const int bid = blockIdx.x;
    const int cpx = (mpanels * 4) >> 3;
    const int swz = (bid & 7) * cpx + (bid >> 3);
    const int bm = (swz >> 2) * 128;
    const int bn = (swz & 3) * 128;

    const int tid  = threadIdx.x;
    const int lane = tid & 63;
    const int wv   = tid >> 6;
    const int wm   = (wv >> 1) * 64;
    const int wn   = (wv & 1) * 64;
    const int ln15 = lane & 15;
    const int ln16 = lane >> 4;

    auto GLDS = [&](const ushort* gbase, int rowbase, ushort* ldsbase, int k0) {
        int rb = wv * 32 + (lane >> 3);
        int c  = lane & 7;
#pragma unroll
        for (int i = 0; i < 4; ++i) {
            int r = rb + i * 8;
            const ushort* src = gbase + (long)(rowbase + r) * 512 + k0 + ((c ^ (r & 7)) << 3);
            ushort* dst = ldsbase + wv * 2048 + i * 512;
            __builtin_amdgcn_global_load_lds((AS1 const void*)src, (AS3 void*)dst, 16, 0, 0);
        }
    };

    ushort* asb0 = lds;
    ushort* asb1 = lds + 8192;
    ushort* wsb[2] = { lds + 16384, lds + 24576 };

    f32x4 acc[4][4] = {};

    auto MFMA_PHASE = [&](ushort* Asb, ushort* Wsb) {
        __builtin_amdgcn_s_setprio(1);
#pragma unroll
        for (int kj = 0; kj < 2; ++kj) {
            bf16x8 af[4], bfv[4];
#pragma unroll
            for (int mi = 0; mi < 4; ++mi) {
                int row = wm + mi * 16 + ln15;
                int ch  = kj * 4 + ln16;
                af[mi] = *(const bf16x8*)&Asb[row * 64 + ((ch ^ (row & 7)) << 3)];
            }
#pragma unroll
            for (int ni = 0; ni < 4; ++ni) {
                int row = wn + ni * 16 + ln15;
                int ch  = kj * 4 + ln16;
                bfv[ni] = *(const bf16x8*)&Wsb[row * 64 + ((ch ^ (row & 7)) << 3)];
            }
#pragma unroll
            for (int mi = 0; mi < 4; ++mi)
#pragma unroll
                for (int ni = 0; ni < 4; ++ni)
                    acc[mi][ni] = __builtin_amdgcn_mfma_f32_16x16x32_bf16(
                        af[mi], bfv[ni], acc[mi][ni], 0, 0, 0);
        }
        __builtin_amdgcn_s_setprio(0);
    };

    GLDS((const ushort*)Ain, bm, asb0, 0);
    GLDS(Wbf, bn, wsb[0], 0);
    asm volatile("s_waitcnt vmcnt(0) lgkmcnt(0)" ::: "memory");
    __builtin_amdgcn_sched_barrier(0);
    __builtin_amdgcn_s_barrier();
    asm volatile("" ::: "memory");
#pragma unroll
    for (int kt = 0; kt < 8; ++kt) {
        ushort* Asb = (kt & 1) ? asb1 : asb0;
        ushort* nAs = (kt & 1) ? asb0 : asb1;
        if (kt < 7) {
            GLDS(Wbf, bn, wsb[(kt + 1) & 1], (kt + 1) * 64);
            GLDS((const ushort*)Ain, bm, nAs, (kt + 1) * 64);
        }
        __builtin_amdgcn_sched_barrier(0);
        MFMA_PHASE(Asb, wsb[kt & 1]);
        asm volatile("s_waitcnt vmcnt(0) lgkmcnt(0)" ::: "memory");
        __builtin_amdgcn_sched_barrier(0);
        __builtin_amdgcn_s_barrier();
        asm volatile("" ::: "memory");
    }

    float bsv[4];
#pragma unroll
    for (int ni = 0; ni < 4; ++ni)
        bsv[ni] = bias[bn + wn + ni * 16 + ln15];

    float* ef = (float*)lds;
#pragma unroll
    for (int half = 0; half < 2; ++half) {
        if (wm == half * 64) {
#pragma unroll
            for (int mi = 0; mi < 4; ++mi)
#pragma unroll
                for (int j = 0; j < 4; ++j) {
                    int lr = mi * 16 + ln16 * 4 + j;
#pragma unroll
                    for (int ni = 0; ni < 4; ++ni) {
                        int col = wn + ni * 16 + ln15;
                        int cs  = col ^ ((lr & 12) << 2);
                        ef[lr * 128 + cs] = acc[mi][ni][j] + bsv[ni];
                    }
                }
        }
        asm volatile("s_waitcnt lgkmcnt(0)" ::: "memory");
        __builtin_amdgcn_sched_barrier(0);
        __builtin_amdgcn_s_barrier();
        asm volatile("" ::: "memory");
#pragma unroll
        for (int i = 0; i < 8; ++i) {
            int idx = i * 1024 + tid * 4;
            int lr = idx >> 7, col = idx & 127;
            int cs = col ^ ((lr & 12) << 2);
            float4 v = *(const float4*)&ef[lr * 128 + cs];
            *(float4*)((float*)out + (long)(bm + half * 64 + lr) * 512 + bn + col) = v;
        }
        if (half == 0) {
            asm volatile("" ::: "memory");
            __builtin_amdgcn_s_barrier();
            asm volatile("" ::: "memory");
        }
    }
}

// ---------------------------------------------------------------------------
extern "C" void kernel_launch(void* const* d_in, const int* in_sizes, int n_in,
                              void* d_out, int out_size, void* d_ws, size_t ws_size,
                              hipStream_t stream) {
    const float* query = (const float*)d_in[0];
    const float* key   = (const float*)d_in[1];
    const float* value = (const float*)d_in[2];
    const int*   mask  = (const int*)d_in[3];
    const float* Wq = (const float*)d_in[4];
    const float* bq = (const float*)d_in[5];
    const float* Wk = (const float*)d_in[6];
    const float* bk = (const float*)d_in[7];
    const float* Wv = (const float*)d_in[8];
    const float* bv = (const float*)d_in[9];
    const float* Wo = (const float*)d_in[10];
    const float* bo = (const float*)d_in[11];
    float* out = (float*)d_out;

    char* ws = (char*)d_ws;
    ushort* Wqbf  = (ushort*)(ws + 0);                  // 512 KB
    ushort* Wobf  = (ushort*)(ws + 524288u);            // 512 KB
    float*  WkT   = (float*)(ws + (1u << 20));          // 1 MB
    float*  WvT   = (float*)(ws + (2u << 20));          // 1 MB
    float*  kproj = (float*)(ws + (3u << 20));          // 256 KB
    float*  vproj = (float*)(ws + (3u << 20) + 262144u);
    ushort* xbf   = (ushort*)(ws + (4u << 20));         // 8 MB (8192 x 512 bf16)

    convert2<<<dim3(256, 2), 256, 0, stream>>>(Wq, Wo, Wqbf, Wobf);
    transpose2<<<dim3(16, 16, 2), dim3(32, 8), 0, stream>>>(Wk, Wv, WkT, WvT);

    kv_proj<<<B_ * S_, 512, 0, stream>>>(key, value, WkT, WvT, bk, bv, kproj, vproj);

    // fused q-projection + two-stage attention: 512 blocks x 16 t-rows, wave=head
    qattn<<<512, 512, 0, stream>>>(query, Wqbf, bq, kproj, vproj, mask, xbf);

    // output projection: M = 8192, bf16 A, fp32 out
    gemm_mfma<1, 0><<<256, 256, 0, stream>>>(xbf, Wobf, bo, out, 64);

    (void)in_sizes; (void)n_in; (void)out_size; (void)ws_size;
}